// Round 4
// baseline (820.233 us; speedup 1.0000x reference)
//
#include <hip/hip_runtime.h>
#include <hip/hip_bf16.h>
#include <stdint.h>

#define LSEQ   16384
#define NBATCH 8
#define MROWS  (NBATCH*LSEQ)   // 131072
#define CDIM   256
#define NHEADS 8
#define HDIM   32
#define NWIN   64
#define NSH    32
#define NHID   1024

typedef unsigned short u16;
typedef __attribute__((ext_vector_type(4))) float f32x4;
typedef __attribute__((ext_vector_type(8))) short s16x8;

__device__ __forceinline__ u16 f2bf(float f) {
  union { float f; unsigned u; } c; c.f = f;
  unsigned r = c.u + 0x7FFFu + ((c.u >> 16) & 1u);
  return (u16)(r >> 16);
}

// ---------------- weight transpose fp32->bf16: out[n][k] = in[k][n] ----------------
__global__ __launch_bounds__(256) void wtrans_kernel(const float* __restrict__ in,
                                                     u16* __restrict__ out, int K, int N) {
  __shared__ float tile[64][65];
  int k0 = blockIdx.x * 64, n0 = blockIdx.y * 64;
  int t = threadIdx.x;
  int r = t >> 4, cb = (t & 15) * 4;
#pragma unroll
  for (int p = 0; p < 4; ++p) {
    const float4 v = *(const float4*)(in + (size_t)(k0 + r + p*16) * N + n0 + cb);
    tile[r+p*16][cb+0] = v.x; tile[r+p*16][cb+1] = v.y;
    tile[r+p*16][cb+2] = v.z; tile[r+p*16][cb+3] = v.w;
  }
  __syncthreads();
#pragma unroll
  for (int p = 0; p < 4; ++p) {
    int nl = r + p*16;
    ushort4 o;
    o.x = f2bf(tile[cb+0][nl]); o.y = f2bf(tile[cb+1][nl]);
    o.z = f2bf(tile[cb+2][nl]); o.w = f2bf(tile[cb+3][nl]);
    *(ushort4*)(out + (size_t)(n0+nl)*K + k0 + cb) = o;
  }
}

// ---------------- LN1 + shift(-32, zero tail) -> bf16 ----------------
__global__ __launch_bounds__(256) void ln_shift_kernel(const float* __restrict__ x,
                                                       const float* __restrict__ g,
                                                       const float* __restrict__ b,
                                                       u16* __restrict__ out) {
  int row  = blockIdx.x * 4 + (threadIdx.x >> 6);
  int lane = threadIdx.x & 63;
  u16* op = out + (size_t)row * CDIM + lane*4;
  int l  = row & (LSEQ-1);
  int ls = l + NSH;
  if (ls >= LSEQ) { *(ushort4*)op = make_ushort4(0,0,0,0); return; }
  const float4 v = *(const float4*)(x + ((size_t)(row - l) + ls) * CDIM + lane*4);
  float s  = v.x+v.y+v.z+v.w;
  float s2 = v.x*v.x + v.y*v.y + v.z*v.z + v.w*v.w;
#pragma unroll
  for (int m = 1; m < 64; m <<= 1) { s += __shfl_xor(s, m); s2 += __shfl_xor(s2, m); }
  float mean = s * (1.f/CDIM);
  float rs = rsqrtf(s2*(1.f/CDIM) - mean*mean + 1e-5f);
  const float4 gv = *(const float4*)(g + lane*4);
  const float4 bv = *(const float4*)(b + lane*4);
  ushort4 o;
  o.x = f2bf((v.x-mean)*rs*gv.x + bv.x);
  o.y = f2bf((v.y-mean)*rs*gv.y + bv.y);
  o.z = f2bf((v.z-mean)*rs*gv.z + bv.z);
  o.w = f2bf((v.w-mean)*rs*gv.w + bv.w);
  *(ushort4*)op = o;
}

// ---------------- LN2: fix rows l<32 of x1 (=x), LN -> bf16 ----------------
__global__ __launch_bounds__(256) void ln2_kernel(const float* __restrict__ x,
                                                  float* __restrict__ x1,
                                                  const float* __restrict__ g,
                                                  const float* __restrict__ b,
                                                  u16* __restrict__ out) {
  int row  = blockIdx.x * 4 + (threadIdx.x >> 6);
  int lane = threadIdx.x & 63;
  int l = row & (LSEQ-1);
  float* dp = x1 + (size_t)row * CDIM + lane*4;
  float4 v;
  if (l < NSH) { v = *(const float4*)(x + (size_t)row * CDIM + lane*4); *(float4*)dp = v; }
  else         { v = *(const float4*)dp; }
  float s  = v.x+v.y+v.z+v.w;
  float s2 = v.x*v.x + v.y*v.y + v.z*v.z + v.w*v.w;
#pragma unroll
  for (int m = 1; m < 64; m <<= 1) { s += __shfl_xor(s, m); s2 += __shfl_xor(s2, m); }
  float mean = s * (1.f/CDIM);
  float rs = rsqrtf(s2*(1.f/CDIM) - mean*mean + 1e-5f);
  const float4 gv = *(const float4*)(g + lane*4);
  const float4 bv = *(const float4*)(b + lane*4);
  ushort4 o;
  o.x = f2bf((v.x-mean)*rs*gv.x + bv.x);
  o.y = f2bf((v.y-mean)*rs*gv.y + bv.y);
  o.z = f2bf((v.z-mean)*rs*gv.z + bv.z);
  o.w = f2bf((v.w-mean)*rs*gv.w + bv.w);
  *(ushort4*)(out + (size_t)row * CDIM + lane*4) = o;
}

// ---------------- GEMM: C[M,N] = A[M,K] * BT[N,K]^T, 128x128x64 tiles ----------------
// EPI: 0=bf16 +bias (qkv), 1=proj(+bias, unshift, +x residual -> fp32),
//      2=fc1(+bias, gelu -> bf16), 3=fc2(+bias, +res -> fp32)
template<int KDIM, int NDIM, int EPI>
__global__ __launch_bounds__(256) void gemm_kernel(const u16* __restrict__ A,
                                                   const u16* __restrict__ BT,
                                                   const float* __restrict__ bias,
                                                   void* __restrict__ Cout,
                                                   const float* __restrict__ res) {
  __shared__ __align__(16) u16 As[128*64];
  __shared__ __align__(16) u16 Bs[128*64];
  const int t = threadIdx.x, wave = t >> 6, lane = t & 63;
  const int tm = blockIdx.x, tn = blockIdx.y;
  f32x4 acc[4][4];
#pragma unroll
  for (int m = 0; m < 4; ++m)
#pragma unroll
    for (int n = 0; n < 4; ++n) acc[m][n] = (f32x4){0.f,0.f,0.f,0.f};

  const size_t Aoff = (size_t)tm * 128 * KDIM;
  const size_t Boff = (size_t)tn * 128 * KDIM;
  int rowS[4], kblkS[4];
#pragma unroll
  for (int p = 0; p < 4; ++p) {
    int i = p*256 + t; rowS[p] = i >> 3;
    kblkS[p] = ((i & 7) ^ (rowS[p] & 7)) * 8;   // inverse-swizzled global k-block
  }
  const int wr = (wave >> 1) * 64, wc = (wave & 1) * 64;

  for (int kt = 0; kt < KDIM/64; ++kt) {
    const int k0 = kt * 64;
#pragma unroll
    for (int p = 0; p < 4; ++p) {
      __builtin_amdgcn_global_load_lds(
        (const __attribute__((address_space(1))) void*)(A + Aoff + (size_t)rowS[p]*KDIM + k0 + kblkS[p]),
        (__attribute__((address_space(3))) void*)(As + (p*256 + wave*64)*8), 16, 0, 0);
      __builtin_amdgcn_global_load_lds(
        (const __attribute__((address_space(1))) void*)(BT + Boff + (size_t)rowS[p]*KDIM + k0 + kblkS[p]),
        (__attribute__((address_space(3))) void*)(Bs + (p*256 + wave*64)*8), 16, 0, 0);
    }
    asm volatile("s_waitcnt vmcnt(0)" ::: "memory");
    __syncthreads();
#pragma unroll
    for (int kk = 0; kk < 2; ++kk) {
      s16x8 af[4], bf[4];
#pragma unroll
      for (int m = 0; m < 4; ++m) {
        int r = wr + m*16 + (lane & 15);
        int slot = (kk*4 + (lane >> 4)) ^ (r & 7);
        af[m] = *(const s16x8*)&As[r*64 + slot*8];
      }
#pragma unroll
      for (int n = 0; n < 4; ++n) {
        int r = wc + n*16 + (lane & 15);
        int slot = (kk*4 + (lane >> 4)) ^ (r & 7);
        bf[n] = *(const s16x8*)&Bs[r*64 + slot*8];
      }
#pragma unroll
      for (int m = 0; m < 4; ++m)
#pragma unroll
        for (int n = 0; n < 4; ++n)
          acc[m][n] = __builtin_amdgcn_mfma_f32_16x16x32_bf16(af[m], bf[n], acc[m][n], 0, 0, 0);
    }
    __syncthreads();
  }

  const int g = lane >> 4, c0 = lane & 15;
  const size_t row0 = (size_t)tm*128 + wr;
  const int col0 = tn*128 + wc;
  float bv[4];
#pragma unroll
  for (int n = 0; n < 4; ++n) bv[n] = bias[col0 + n*16 + c0];

  if constexpr (EPI == 0) {
    u16* out = (u16*)Cout;
#pragma unroll
    for (int m = 0; m < 4; ++m)
#pragma unroll
      for (int j = 0; j < 4; ++j) {
        size_t row = row0 + m*16 + g*4 + j;
        u16* orow = out + row * NDIM + col0 + c0;
#pragma unroll
        for (int n = 0; n < 4; ++n) orow[n*16] = f2bf(acc[m][n][j] + bv[n]);
      }
  } else if constexpr (EPI == 1) {
    float* out = (float*)Cout;
#pragma unroll
    for (int m = 0; m < 4; ++m)
#pragma unroll
      for (int j = 0; j < 4; ++j) {
        size_t rp = row0 + m*16 + g*4 + j;
        int l = (int)(rp & (LSEQ-1));
        if (l < LSEQ - NSH) {
          size_t dr = rp + NSH;
          const float* rrow = res + dr*CDIM + col0 + c0;
          float* orow = out + dr*CDIM + col0 + c0;
#pragma unroll
          for (int n = 0; n < 4; ++n) orow[n*16] = rrow[n*16] + acc[m][n][j] + bv[n];
        }
      }
  } else if constexpr (EPI == 2) {
    u16* out = (u16*)Cout;
#pragma unroll
    for (int m = 0; m < 4; ++m)
#pragma unroll
      for (int j = 0; j < 4; ++j) {
        size_t row = row0 + m*16 + g*4 + j;
        u16* orow = out + row * NDIM + col0 + c0;
#pragma unroll
        for (int n = 0; n < 4; ++n) {
          float v = acc[m][n][j] + bv[n];
          orow[n*16] = f2bf(0.5f*v*(1.f + erff(v*0.70710678118654752f)));
        }
      }
  } else {
    float* out = (float*)Cout;
#pragma unroll
    for (int m = 0; m < 4; ++m)
#pragma unroll
      for (int j = 0; j < 4; ++j) {
        size_t row = row0 + m*16 + g*4 + j;
        size_t o = row * NDIM + col0 + c0;
#pragma unroll
        for (int n = 0; n < 4; ++n) out[o + n*16] = res[o + n*16] + acc[m][n][j] + bv[n];
      }
  }
}

// ---------------- windowed attention ----------------
__global__ __launch_bounds__(256) void attn_kernel(const u16* __restrict__ qkv,
                                                   const float* __restrict__ rpb,
                                                   u16* __restrict__ out) {
  __shared__ __align__(16) u16 VT[NHEADS*HDIM*NWIN]; // [h][d][c], xor-swizzled, 32KB
  __shared__ __align__(16) u16 Pl[4*NWIN*NWIN];      // per-wave P, swizzled, 32KB
  __shared__ float biasl[NHEADS][128];
  const int t = threadIdx.x, wave = t >> 6, lane = t & 63;
  const int g = lane >> 4, c0 = lane & 15;
  const size_t rowbase = (size_t)blockIdx.x * NWIN;

  for (int e = t; e < NHEADS*128; e += 256) {
    int h = e >> 7, i = e & 127;
    biasl[h][i] = (i < 2*NWIN-1) ? rpb[i*NHEADS + h] : 0.f;
  }
  { // V transpose staging: VT[h][d][c] = v[c][d]
    int cA = t >> 5;
    int inner = t & 31;
    int hh = inner >> 2, d0 = (inner & 3) * 8;
#pragma unroll
    for (int p = 0; p < 8; ++p) {
      int c = p*8 + cA;
      s16x8 v = *(const s16x8*)&qkv[(rowbase + c)*768 + 512 + hh*32 + d0];
#pragma unroll
      for (int j = 0; j < 8; ++j) {
        int d = d0 + j;
        int slot = (c >> 3) ^ (d & 7) ^ hh;
        *(u16*)((char*)VT + hh*4096 + d*128 + slot*16 + (c & 7)*2) = (u16)v[j];
      }
    }
  }
  __syncthreads();

  const float scale = 0.17677669529663687f; // 32^-0.5
#pragma unroll 1
  for (int rep = 0; rep < 2; ++rep) {
    const int h = wave*2 + rep;
    s16x8 qf[4], kf[4];
#pragma unroll
    for (int m = 0; m < 4; ++m)
      qf[m] = *(const s16x8*)&qkv[(rowbase + m*16 + c0)*768 + h*32 + g*8];
#pragma unroll
    for (int n = 0; n < 4; ++n)
      kf[n] = *(const s16x8*)&qkv[(rowbase + n*16 + c0)*768 + 256 + h*32 + g*8];
    f32x4 sa[4][4];
#pragma unroll
    for (int m = 0; m < 4; ++m)
#pragma unroll
      for (int n = 0; n < 4; ++n) sa[m][n] = (f32x4){0.f,0.f,0.f,0.f};
#pragma unroll
    for (int m = 0; m < 4; ++m)
#pragma unroll
      for (int n = 0; n < 4; ++n)
        sa[m][n] = __builtin_amdgcn_mfma_f32_16x16x32_bf16(qf[m], kf[n], sa[m][n], 0, 0, 0);
    // scale + relative position bias
#pragma unroll
    for (int m = 0; m < 4; ++m)
#pragma unroll
      for (int n = 0; n < 4; ++n) {
        int idx0 = (m-n)*16 + 4*g - c0 + 63;
#pragma unroll
        for (int j = 0; j < 4; ++j)
          sa[m][n][j] = sa[m][n][j]*scale + biasl[h][idx0 + j];
      }
    // softmax (rows spread over 16 lanes of same g-group x 4 n-regs)
    float rm[4][4], rsum[4][4];
#pragma unroll
    for (int m = 0; m < 4; ++m)
#pragma unroll
      for (int j = 0; j < 4; ++j) {
        float mx = fmaxf(fmaxf(sa[m][0][j], sa[m][1][j]), fmaxf(sa[m][2][j], sa[m][3][j]));
        mx = fmaxf(mx, __shfl_xor(mx, 1));
        mx = fmaxf(mx, __shfl_xor(mx, 2));
        mx = fmaxf(mx, __shfl_xor(mx, 4));
        mx = fmaxf(mx, __shfl_xor(mx, 8));
        rm[m][j] = mx;
      }
#pragma unroll
    for (int m = 0; m < 4; ++m)
#pragma unroll
      for (int n = 0; n < 4; ++n)
#pragma unroll
        for (int j = 0; j < 4; ++j)
          sa[m][n][j] = expf(sa[m][n][j] - rm[m][j]);
#pragma unroll
    for (int m = 0; m < 4; ++m)
#pragma unroll
      for (int j = 0; j < 4; ++j) {
        float s = sa[m][0][j] + sa[m][1][j] + sa[m][2][j] + sa[m][3][j];
        s += __shfl_xor(s, 1);
        s += __shfl_xor(s, 2);
        s += __shfl_xor(s, 4);
        s += __shfl_xor(s, 8);
        rsum[m][j] = 1.f / s;
      }
    // write P (bf16, swizzled)
    asm volatile("s_waitcnt lgkmcnt(0)" ::: "memory");
#pragma unroll
    for (int m = 0; m < 4; ++m)
#pragma unroll
      for (int n = 0; n < 4; ++n)
#pragma unroll
        for (int j = 0; j < 4; ++j) {
          int r = m*16 + 4*g + j, c = n*16 + c0;
          *(u16*)((char*)Pl + wave*8192 + r*128 + (((c>>3)^(r&7))*16) + (c&7)*2)
            = f2bf(sa[m][n][j] * rsum[m][j]);
        }
    asm volatile("s_waitcnt lgkmcnt(0)" ::: "memory");
    __builtin_amdgcn_sched_barrier(0);
    // PV
    f32x4 oa[4][2];
#pragma unroll
    for (int m = 0; m < 4; ++m) { oa[m][0] = (f32x4){0.f,0.f,0.f,0.f}; oa[m][1] = (f32x4){0.f,0.f,0.f,0.f}; }
#pragma unroll
    for (int kk = 0; kk < 2; ++kk) {
      s16x8 pa[4], vb[2];
#pragma unroll
      for (int m = 0; m < 4; ++m) {
        int r = m*16 + c0;
        int slot = (kk*4 + g) ^ (r & 7);
        pa[m] = *(const s16x8*)((const char*)Pl + wave*8192 + r*128 + slot*16);
      }
#pragma unroll
      for (int n = 0; n < 2; ++n) {
        int d = n*16 + c0;
        int slot = (kk*4 + g) ^ (d & 7) ^ h;
        vb[n] = *(const s16x8*)((const char*)VT + h*4096 + d*128 + slot*16);
      }
#pragma unroll
      for (int m = 0; m < 4; ++m)
#pragma unroll
        for (int n = 0; n < 2; ++n)
          oa[m][n] = __builtin_amdgcn_mfma_f32_16x16x32_bf16(pa[m], vb[n], oa[m][n], 0, 0, 0);
    }
#pragma unroll
    for (int m = 0; m < 4; ++m)
#pragma unroll
      for (int n = 0; n < 2; ++n)
#pragma unroll
        for (int j = 0; j < 4; ++j) {
          int r = m*16 + 4*g + j, d = n*16 + c0;
          out[(rowbase + r)*CDIM + h*32 + d] = f2bf(oa[m][n][j]);
        }
  }
}

extern "C" void kernel_launch(void* const* d_in, const int* in_sizes, int n_in,
                              void* d_out, int out_size, void* d_ws, size_t ws_size,
                              hipStream_t stream) {
  const float* x      = (const float*)d_in[0];
  const float* g1     = (const float*)d_in[1];
  const float* b1     = (const float*)d_in[2];
  const float* qkv_w  = (const float*)d_in[3];
  const float* qkv_b  = (const float*)d_in[4];
  const float* rpb    = (const float*)d_in[5];
  const float* proj_w = (const float*)d_in[6];
  const float* proj_b = (const float*)d_in[7];
  const float* g2     = (const float*)d_in[8];
  const float* b2     = (const float*)d_in[9];
  const float* fc1_w  = (const float*)d_in[10];
  const float* fc1_b  = (const float*)d_in[11];
  const float* fc2_w  = (const float*)d_in[12];
  const float* fc2_b  = (const float*)d_in[13];
  float* out = (float*)d_out;

  // workspace layout (bf16 elements):
  // R0: qkv          M*768
  // R1: xnshift/attnout (M*256) then h (M*1024)
  // WT: transposed bf16 weights
  u16* R0     = (u16*)d_ws;
  u16* R1     = R0 + (size_t)MROWS*768;
  u16* qkvwT  = R1 + (size_t)MROWS*1024;
  u16* projwT = qkvwT + 768*256;
  u16* fc1wT  = projwT + 256*256;
  u16* fc2wT  = fc1wT + 1024*256;

  wtrans_kernel<<<dim3(4, 12), 256, 0, stream>>>(qkv_w, qkvwT, 256, 768);
  wtrans_kernel<<<dim3(4, 4),  256, 0, stream>>>(proj_w, projwT, 256, 256);
  wtrans_kernel<<<dim3(4, 16), 256, 0, stream>>>(fc1_w, fc1wT, 256, 1024);
  wtrans_kernel<<<dim3(16, 4), 256, 0, stream>>>(fc2_w, fc2wT, 1024, 256);

  ln_shift_kernel<<<MROWS/4, 256, 0, stream>>>(x, g1, b1, R1);
  gemm_kernel<256, 768, 0><<<dim3(MROWS/128, 6), 256, 0, stream>>>(R1, qkvwT, qkv_b, R0, nullptr);
  attn_kernel<<<MROWS/NWIN, 256, 0, stream>>>(R0, rpb, R1);
  gemm_kernel<256, 256, 1><<<dim3(MROWS/128, 2), 256, 0, stream>>>(R1, projwT, proj_b, out, x);
  ln2_kernel<<<MROWS/4, 256, 0, stream>>>(x, out, g2, b2, R0);
  gemm_kernel<256, 1024, 2><<<dim3(MROWS/128, 8), 256, 0, stream>>>(R0, fc1wT, fc1_b, R1, nullptr);
  gemm_kernel<1024, 256, 3><<<dim3(MROWS/128, 2), 256, 0, stream>>>(R1, fc2wT, fc2_b, out, out);
}

// Round 5
// 687.100 us; speedup vs baseline: 1.1938x; 1.1938x over previous
//
#include <hip/hip_runtime.h>
#include <hip/hip_bf16.h>
#include <stdint.h>

#define LSEQ   16384
#define NBATCH 8
#define MROWS  (NBATCH*LSEQ)   // 131072
#define CDIM   256
#define NHEADS 8
#define HDIM   32
#define NWIN   64
#define NSH    32
#define NHID   1024

typedef unsigned short u16;
typedef __attribute__((ext_vector_type(4))) float f32x4;
typedef __attribute__((ext_vector_type(8))) short s16x8;

__device__ __forceinline__ u16 f2bf(float f) {
  union { float f; unsigned u; } c; c.f = f;
  unsigned r = c.u + 0x7FFFu + ((c.u >> 16) & 1u);
  return (u16)(r >> 16);
}

// fast GELU: x*sigmoid(1.5957691*(x+0.044715x^3)) == tanh-approx GELU
__device__ __forceinline__ float gelu_fast(float v) {
  float t = v * v;
  float u2 = v * fmaf(t, 0.0713548162726f, 1.59576912161f); // 2*0.7978845608*(1, 0.044715)
  float e = __expf(u2);
  float r = __builtin_amdgcn_rcpf(e + 1.f);
  return fmaf(-v, r, v); // v*e/(e+1)
}

// ---------------- weight transpose fp32->bf16: out[n][k] = in[k][n] ----------------
__global__ __launch_bounds__(256) void wtrans_kernel(const float* __restrict__ in,
                                                     u16* __restrict__ out, int K, int N) {
  __shared__ float tile[64][65];
  int k0 = blockIdx.x * 64, n0 = blockIdx.y * 64;
  int t = threadIdx.x;
  int r = t >> 4, cb = (t & 15) * 4;
#pragma unroll
  for (int p = 0; p < 4; ++p) {
    const float4 v = *(const float4*)(in + (size_t)(k0 + r + p*16) * N + n0 + cb);
    tile[r+p*16][cb+0] = v.x; tile[r+p*16][cb+1] = v.y;
    tile[r+p*16][cb+2] = v.z; tile[r+p*16][cb+3] = v.w;
  }
  __syncthreads();
#pragma unroll
  for (int p = 0; p < 4; ++p) {
    int nl = r + p*16;
    ushort4 o;
    o.x = f2bf(tile[cb+0][nl]); o.y = f2bf(tile[cb+1][nl]);
    o.z = f2bf(tile[cb+2][nl]); o.w = f2bf(tile[cb+3][nl]);
    *(ushort4*)(out + (size_t)(n0+nl)*K + k0 + cb) = o;
  }
}

// ---------------- LN1 + shift(-32, zero tail) -> bf16 ----------------
__global__ __launch_bounds__(256) void ln_shift_kernel(const float* __restrict__ x,
                                                       const float* __restrict__ g,
                                                       const float* __restrict__ b,
                                                       u16* __restrict__ out) {
  int row  = blockIdx.x * 4 + (threadIdx.x >> 6);
  int lane = threadIdx.x & 63;
  u16* op = out + (size_t)row * CDIM + lane*4;
  int l  = row & (LSEQ-1);
  int ls = l + NSH;
  if (ls >= LSEQ) { *(ushort4*)op = make_ushort4(0,0,0,0); return; }
  const float4 v = *(const float4*)(x + ((size_t)(row - l) + ls) * CDIM + lane*4);
  float s  = v.x+v.y+v.z+v.w;
  float s2 = v.x*v.x + v.y*v.y + v.z*v.z + v.w*v.w;
#pragma unroll
  for (int m = 1; m < 64; m <<= 1) { s += __shfl_xor(s, m); s2 += __shfl_xor(s2, m); }
  float mean = s * (1.f/CDIM);
  float rs = rsqrtf(s2*(1.f/CDIM) - mean*mean + 1e-5f);
  const float4 gv = *(const float4*)(g + lane*4);
  const float4 bv = *(const float4*)(b + lane*4);
  ushort4 o;
  o.x = f2bf((v.x-mean)*rs*gv.x + bv.x);
  o.y = f2bf((v.y-mean)*rs*gv.y + bv.y);
  o.z = f2bf((v.z-mean)*rs*gv.z + bv.z);
  o.w = f2bf((v.w-mean)*rs*gv.w + bv.w);
  *(ushort4*)op = o;
}

// ---------------- LN2: fix rows l<32 of x1 (=x), LN -> bf16 ----------------
__global__ __launch_bounds__(256) void ln2_kernel(const float* __restrict__ x,
                                                  float* __restrict__ x1,
                                                  const float* __restrict__ g,
                                                  const float* __restrict__ b,
                                                  u16* __restrict__ out) {
  int row  = blockIdx.x * 4 + (threadIdx.x >> 6);
  int lane = threadIdx.x & 63;
  int l = row & (LSEQ-1);
  float* dp = x1 + (size_t)row * CDIM + lane*4;
  float4 v;
  if (l < NSH) { v = *(const float4*)(x + (size_t)row * CDIM + lane*4); *(float4*)dp = v; }
  else         { v = *(const float4*)dp; }
  float s  = v.x+v.y+v.z+v.w;
  float s2 = v.x*v.x + v.y*v.y + v.z*v.z + v.w*v.w;
#pragma unroll
  for (int m = 1; m < 64; m <<= 1) { s += __shfl_xor(s, m); s2 += __shfl_xor(s2, m); }
  float mean = s * (1.f/CDIM);
  float rs = rsqrtf(s2*(1.f/CDIM) - mean*mean + 1e-5f);
  const float4 gv = *(const float4*)(g + lane*4);
  const float4 bv = *(const float4*)(b + lane*4);
  ushort4 o;
  o.x = f2bf((v.x-mean)*rs*gv.x + bv.x);
  o.y = f2bf((v.y-mean)*rs*gv.y + bv.y);
  o.z = f2bf((v.z-mean)*rs*gv.z + bv.z);
  o.w = f2bf((v.w-mean)*rs*gv.w + bv.w);
  *(ushort4*)(out + (size_t)row * CDIM + lane*4) = o;
}

// ---------------- GEMM: C[M,N] = A[M,K] * BT[N,K]^T, 128x128x64 tiles ----------------
// 1D grid with supertile remap: tn innermost over chunks of G tm-tiles
// (A-panel chunk 32*64KB=2MB fits per-XCD L2; reuse distance G blocks; G%8==0 -> same XCD)
// EPI: 0=bf16 +bias (qkv), 1=proj(+bias, unshift, +x residual -> fp32),
//      2=fc1(+bias, gelu -> bf16), 3=fc2(+bias, +res -> fp32)
template<int KDIM, int NDIM, int EPI>
__global__ __launch_bounds__(256) void gemm_kernel(const u16* __restrict__ A,
                                                   const u16* __restrict__ BT,
                                                   const float* __restrict__ bias,
                                                   void* __restrict__ Cout,
                                                   const float* __restrict__ res) {
  __shared__ __align__(16) u16 As[128*64];
  __shared__ __align__(16) u16 Bs[128*64];
  const int t = threadIdx.x, wave = t >> 6, lane = t & 63;
  constexpr int NT_N = NDIM / 128;
  constexpr int G = 32;
  const int bid = blockIdx.x;
  const int chunk = bid / (G * NT_N);
  const int rem = bid - chunk * (G * NT_N);
  const int tn = rem / G;
  const int tm = chunk * G + (rem - tn * G);
  f32x4 acc[4][4];
#pragma unroll
  for (int m = 0; m < 4; ++m)
#pragma unroll
    for (int n = 0; n < 4; ++n) acc[m][n] = (f32x4){0.f,0.f,0.f,0.f};

  const size_t Aoff = (size_t)tm * 128 * KDIM;
  const size_t Boff = (size_t)tn * 128 * KDIM;
  int rowS[4], kblkS[4];
#pragma unroll
  for (int p = 0; p < 4; ++p) {
    int i = p*256 + t; rowS[p] = i >> 3;
    kblkS[p] = ((i & 7) ^ (rowS[p] & 7)) * 8;   // inverse-swizzled global k-block
  }
  const int wr = (wave >> 1) * 64, wc = (wave & 1) * 64;

  for (int kt = 0; kt < KDIM/64; ++kt) {
    const int k0 = kt * 64;
#pragma unroll
    for (int p = 0; p < 4; ++p) {
      __builtin_amdgcn_global_load_lds(
        (const __attribute__((address_space(1))) void*)(A + Aoff + (size_t)rowS[p]*KDIM + k0 + kblkS[p]),
        (__attribute__((address_space(3))) void*)(As + (p*256 + wave*64)*8), 16, 0, 0);
      __builtin_amdgcn_global_load_lds(
        (const __attribute__((address_space(1))) void*)(BT + Boff + (size_t)rowS[p]*KDIM + k0 + kblkS[p]),
        (__attribute__((address_space(3))) void*)(Bs + (p*256 + wave*64)*8), 16, 0, 0);
    }
    asm volatile("s_waitcnt vmcnt(0)" ::: "memory");
    __syncthreads();
#pragma unroll
    for (int kk = 0; kk < 2; ++kk) {
      s16x8 af[4], bf[4];
#pragma unroll
      for (int m = 0; m < 4; ++m) {
        int r = wr + m*16 + (lane & 15);
        int slot = (kk*4 + (lane >> 4)) ^ (r & 7);
        af[m] = *(const s16x8*)&As[r*64 + slot*8];
      }
#pragma unroll
      for (int n = 0; n < 4; ++n) {
        int r = wc + n*16 + (lane & 15);
        int slot = (kk*4 + (lane >> 4)) ^ (r & 7);
        bf[n] = *(const s16x8*)&Bs[r*64 + slot*8];
      }
#pragma unroll
      for (int m = 0; m < 4; ++m)
#pragma unroll
        for (int n = 0; n < 4; ++n)
          acc[m][n] = __builtin_amdgcn_mfma_f32_16x16x32_bf16(af[m], bf[n], acc[m][n], 0, 0, 0);
    }
    __syncthreads();
  }

  const int g = lane >> 4, c0 = lane & 15;
  const size_t row0 = (size_t)tm*128 + wr;
  const int col0 = tn*128 + wc;
  float bv[4];
#pragma unroll
  for (int n = 0; n < 4; ++n) bv[n] = bias[col0 + n*16 + c0];

  if constexpr (EPI == 0) {
    u16* out = (u16*)Cout;
#pragma unroll
    for (int m = 0; m < 4; ++m)
#pragma unroll
      for (int j = 0; j < 4; ++j) {
        size_t row = row0 + m*16 + g*4 + j;
        u16* orow = out + row * NDIM + col0 + c0;
#pragma unroll
        for (int n = 0; n < 4; ++n) orow[n*16] = f2bf(acc[m][n][j] + bv[n]);
      }
  } else if constexpr (EPI == 1) {
    float* out = (float*)Cout;
#pragma unroll
    for (int m = 0; m < 4; ++m)
#pragma unroll
      for (int j = 0; j < 4; ++j) {
        size_t rp = row0 + m*16 + g*4 + j;
        int l = (int)(rp & (LSEQ-1));
        if (l < LSEQ - NSH) {
          size_t dr = rp + NSH;
          const float* rrow = res + dr*CDIM + col0 + c0;
          float* orow = out + dr*CDIM + col0 + c0;
#pragma unroll
          for (int n = 0; n < 4; ++n) orow[n*16] = rrow[n*16] + acc[m][n][j] + bv[n];
        }
      }
  } else if constexpr (EPI == 2) {
    u16* out = (u16*)Cout;
#pragma unroll
    for (int m = 0; m < 4; ++m)
#pragma unroll
      for (int j = 0; j < 4; ++j) {
        size_t row = row0 + m*16 + g*4 + j;
        u16* orow = out + row * NDIM + col0 + c0;
#pragma unroll
        for (int n = 0; n < 4; ++n)
          orow[n*16] = f2bf(gelu_fast(acc[m][n][j] + bv[n]));
      }
  } else {
    float* out = (float*)Cout;
#pragma unroll
    for (int m = 0; m < 4; ++m)
#pragma unroll
      for (int j = 0; j < 4; ++j) {
        size_t row = row0 + m*16 + g*4 + j;
        size_t o = row * NDIM + col0 + c0;
#pragma unroll
        for (int n = 0; n < 4; ++n) out[o + n*16] = res[o + n*16] + acc[m][n][j] + bv[n];
      }
  }
}

// ---------------- windowed attention ----------------
__global__ __launch_bounds__(256) void attn_kernel(const u16* __restrict__ qkv,
                                                   const float* __restrict__ rpb,
                                                   u16* __restrict__ out) {
  __shared__ __align__(16) u16 VT[NHEADS*HDIM*NWIN]; // [h][d][c], xor-swizzled, 32KB
  __shared__ __align__(16) u16 Pl[4*NWIN*NWIN];      // per-wave P, swizzled, 32KB
  __shared__ float biasl[NHEADS][128];
  const int t = threadIdx.x, wave = t >> 6, lane = t & 63;
  const int g = lane >> 4, c0 = lane & 15;
  const size_t rowbase = (size_t)blockIdx.x * NWIN;

  for (int e = t; e < NHEADS*128; e += 256) {
    int h = e >> 7, i = e & 127;
    biasl[h][i] = (i < 2*NWIN-1) ? rpb[i*NHEADS + h] : 0.f;
  }
  { // V transpose staging: VT[h][d][c] = v[c][d]
    int cA = t >> 5;
    int inner = t & 31;
    int hh = inner >> 2, d0 = (inner & 3) * 8;
#pragma unroll
    for (int p = 0; p < 8; ++p) {
      int c = p*8 + cA;
      s16x8 v = *(const s16x8*)&qkv[(rowbase + c)*768 + 512 + hh*32 + d0];
#pragma unroll
      for (int j = 0; j < 8; ++j) {
        int d = d0 + j;
        int slot = (c >> 3) ^ (d & 7) ^ hh;
        *(u16*)((char*)VT + hh*4096 + d*128 + slot*16 + (c & 7)*2) = (u16)v[j];
      }
    }
  }
  __syncthreads();

  const float scale = 0.17677669529663687f; // 32^-0.5
#pragma unroll 1
  for (int rep = 0; rep < 2; ++rep) {
    const int h = wave*2 + rep;
    s16x8 qf[4], kf[4];
#pragma unroll
    for (int m = 0; m < 4; ++m)
      qf[m] = *(const s16x8*)&qkv[(rowbase + m*16 + c0)*768 + h*32 + g*8];
#pragma unroll
    for (int n = 0; n < 4; ++n)
      kf[n] = *(const s16x8*)&qkv[(rowbase + n*16 + c0)*768 + 256 + h*32 + g*8];
    f32x4 sa[4][4];
#pragma unroll
    for (int m = 0; m < 4; ++m)
#pragma unroll
      for (int n = 0; n < 4; ++n) sa[m][n] = (f32x4){0.f,0.f,0.f,0.f};
#pragma unroll
    for (int m = 0; m < 4; ++m)
#pragma unroll
      for (int n = 0; n < 4; ++n)
        sa[m][n] = __builtin_amdgcn_mfma_f32_16x16x32_bf16(qf[m], kf[n], sa[m][n], 0, 0, 0);
    // scale + relative position bias
#pragma unroll
    for (int m = 0; m < 4; ++m)
#pragma unroll
      for (int n = 0; n < 4; ++n) {
        int idx0 = (m-n)*16 + 4*g - c0 + 63;
#pragma unroll
        for (int j = 0; j < 4; ++j)
          sa[m][n][j] = sa[m][n][j]*scale + biasl[h][idx0 + j];
      }
    // softmax (rows spread over 16 lanes of same g-group x 4 n-regs)
    float rm[4][4], rsum[4][4];
#pragma unroll
    for (int m = 0; m < 4; ++m)
#pragma unroll
      for (int j = 0; j < 4; ++j) {
        float mx = fmaxf(fmaxf(sa[m][0][j], sa[m][1][j]), fmaxf(sa[m][2][j], sa[m][3][j]));
        mx = fmaxf(mx, __shfl_xor(mx, 1));
        mx = fmaxf(mx, __shfl_xor(mx, 2));
        mx = fmaxf(mx, __shfl_xor(mx, 4));
        mx = fmaxf(mx, __shfl_xor(mx, 8));
        rm[m][j] = mx;
      }
#pragma unroll
    for (int m = 0; m < 4; ++m)
#pragma unroll
      for (int n = 0; n < 4; ++n)
#pragma unroll
        for (int j = 0; j < 4; ++j)
          sa[m][n][j] = __expf(sa[m][n][j] - rm[m][j]);
#pragma unroll
    for (int m = 0; m < 4; ++m)
#pragma unroll
      for (int j = 0; j < 4; ++j) {
        float s = sa[m][0][j] + sa[m][1][j] + sa[m][2][j] + sa[m][3][j];
        s += __shfl_xor(s, 1);
        s += __shfl_xor(s, 2);
        s += __shfl_xor(s, 4);
        s += __shfl_xor(s, 8);
        rsum[m][j] = 1.f / s;
      }
    // write P (bf16, swizzled)
    asm volatile("s_waitcnt lgkmcnt(0)" ::: "memory");
#pragma unroll
    for (int m = 0; m < 4; ++m)
#pragma unroll
      for (int n = 0; n < 4; ++n)
#pragma unroll
        for (int j = 0; j < 4; ++j) {
          int r = m*16 + 4*g + j, c = n*16 + c0;
          *(u16*)((char*)Pl + wave*8192 + r*128 + (((c>>3)^(r&7))*16) + (c&7)*2)
            = f2bf(sa[m][n][j] * rsum[m][j]);
        }
    asm volatile("s_waitcnt lgkmcnt(0)" ::: "memory");
    __builtin_amdgcn_sched_barrier(0);
    // PV
    f32x4 oa[4][2];
#pragma unroll
    for (int m = 0; m < 4; ++m) { oa[m][0] = (f32x4){0.f,0.f,0.f,0.f}; oa[m][1] = (f32x4){0.f,0.f,0.f,0.f}; }
#pragma unroll
    for (int kk = 0; kk < 2; ++kk) {
      s16x8 pa[4], vb[2];
#pragma unroll
      for (int m = 0; m < 4; ++m) {
        int r = m*16 + c0;
        int slot = (kk*4 + g) ^ (r & 7);
        pa[m] = *(const s16x8*)((const char*)Pl + wave*8192 + r*128 + slot*16);
      }
#pragma unroll
      for (int n = 0; n < 2; ++n) {
        int d = n*16 + c0;
        int slot = (kk*4 + g) ^ (d & 7) ^ h;
        vb[n] = *(const s16x8*)((const char*)VT + h*4096 + d*128 + slot*16);
      }
#pragma unroll
      for (int m = 0; m < 4; ++m)
#pragma unroll
        for (int n = 0; n < 2; ++n)
          oa[m][n] = __builtin_amdgcn_mfma_f32_16x16x32_bf16(pa[m], vb[n], oa[m][n], 0, 0, 0);
    }
#pragma unroll
    for (int m = 0; m < 4; ++m)
#pragma unroll
      for (int n = 0; n < 2; ++n)
#pragma unroll
        for (int j = 0; j < 4; ++j) {
          int r = m*16 + 4*g + j, d = n*16 + c0;
          out[(rowbase + r)*CDIM + h*32 + d] = f2bf(oa[m][n][j]);
        }
  }
}

extern "C" void kernel_launch(void* const* d_in, const int* in_sizes, int n_in,
                              void* d_out, int out_size, void* d_ws, size_t ws_size,
                              hipStream_t stream) {
  const float* x      = (const float*)d_in[0];
  const float* g1     = (const float*)d_in[1];
  const float* b1     = (const float*)d_in[2];
  const float* qkv_w  = (const float*)d_in[3];
  const float* qkv_b  = (const float*)d_in[4];
  const float* rpb    = (const float*)d_in[5];
  const float* proj_w = (const float*)d_in[6];
  const float* proj_b = (const float*)d_in[7];
  const float* g2     = (const float*)d_in[8];
  const float* b2     = (const float*)d_in[9];
  const float* fc1_w  = (const float*)d_in[10];
  const float* fc1_b  = (const float*)d_in[11];
  const float* fc2_w  = (const float*)d_in[12];
  const float* fc2_b  = (const float*)d_in[13];
  float* out = (float*)d_out;

  // workspace layout (bf16 elements):
  // R0: qkv          M*768
  // R1: xnshift/attnout (M*256) then h (M*1024)
  // WT: transposed bf16 weights
  u16* R0     = (u16*)d_ws;
  u16* R1     = R0 + (size_t)MROWS*768;
  u16* qkvwT  = R1 + (size_t)MROWS*1024;
  u16* projwT = qkvwT + 768*256;
  u16* fc1wT  = projwT + 256*256;
  u16* fc2wT  = fc1wT + 1024*256;

  wtrans_kernel<<<dim3(4, 12), 256, 0, stream>>>(qkv_w, qkvwT, 256, 768);
  wtrans_kernel<<<dim3(4, 4),  256, 0, stream>>>(proj_w, projwT, 256, 256);
  wtrans_kernel<<<dim3(4, 16), 256, 0, stream>>>(fc1_w, fc1wT, 256, 1024);
  wtrans_kernel<<<dim3(16, 4), 256, 0, stream>>>(fc2_w, fc2wT, 1024, 256);

  constexpr int NT_M = MROWS/128;
  ln_shift_kernel<<<MROWS/4, 256, 0, stream>>>(x, g1, b1, R1);
  gemm_kernel<256, 768, 0><<<NT_M*6, 256, 0, stream>>>(R1, qkvwT, qkv_b, R0, nullptr);
  attn_kernel<<<MROWS/NWIN, 256, 0, stream>>>(R0, rpb, R1);
  gemm_kernel<256, 256, 1><<<NT_M*2, 256, 0, stream>>>(R1, projwT, proj_b, out, x);
  ln2_kernel<<<MROWS/4, 256, 0, stream>>>(x, out, g2, b2, R0);
  gemm_kernel<256, 1024, 2><<<NT_M*8, 256, 0, stream>>>(R0, fc1wT, fc1_b, R1, nullptr);
  gemm_kernel<1024, 256, 3><<<NT_M*2, 256, 0, stream>>>(R1, fc2wT, fc2_b, out, out);
}

// Round 6
// 668.993 us; speedup vs baseline: 1.2261x; 1.0271x over previous
//
#include <hip/hip_runtime.h>
#include <hip/hip_bf16.h>
#include <stdint.h>

#define LSEQ   16384
#define NBATCH 8
#define MROWS  (NBATCH*LSEQ)   // 131072
#define CDIM   256
#define NHEADS 8
#define HDIM   32
#define NWIN   64
#define NSH    32
#define NHID   1024

typedef unsigned short u16;
typedef __attribute__((ext_vector_type(4))) float f32x4;
typedef __attribute__((ext_vector_type(8))) short s16x8;

__device__ __forceinline__ u16 f2bf(float f) {
  union { float f; unsigned u; } c; c.f = f;
  unsigned r = c.u + 0x7FFFu + ((c.u >> 16) & 1u);
  return (u16)(r >> 16);
}

// fast GELU: x*sigmoid(1.5957691*(x+0.044715x^3)) == tanh-approx GELU
__device__ __forceinline__ float gelu_fast(float v) {
  float t = v * v;
  float u2 = v * fmaf(t, 0.0713548162726f, 1.59576912161f);
  float e = __expf(u2);
  float r = __builtin_amdgcn_rcpf(e + 1.f);
  return fmaf(-v, r, v); // v*e/(e+1)
}

// ---------------- weight transpose fp32->bf16: out[n][k] = in[k][n] ----------------
__global__ __launch_bounds__(256) void wtrans_kernel(const float* __restrict__ in,
                                                     u16* __restrict__ out, int K, int N) {
  __shared__ float tile[64][65];
  int k0 = blockIdx.x * 64, n0 = blockIdx.y * 64;
  int t = threadIdx.x;
  int r = t >> 4, cb = (t & 15) * 4;
#pragma unroll
  for (int p = 0; p < 4; ++p) {
    const float4 v = *(const float4*)(in + (size_t)(k0 + r + p*16) * N + n0 + cb);
    tile[r+p*16][cb+0] = v.x; tile[r+p*16][cb+1] = v.y;
    tile[r+p*16][cb+2] = v.z; tile[r+p*16][cb+3] = v.w;
  }
  __syncthreads();
#pragma unroll
  for (int p = 0; p < 4; ++p) {
    int nl = r + p*16;
    ushort4 o;
    o.x = f2bf(tile[cb+0][nl]); o.y = f2bf(tile[cb+1][nl]);
    o.z = f2bf(tile[cb+2][nl]); o.w = f2bf(tile[cb+3][nl]);
    *(ushort4*)(out + (size_t)(n0+nl)*K + k0 + cb) = o;
  }
}

// ---------------- LN1 + shift(-32, zero tail) -> bf16 ----------------
__global__ __launch_bounds__(256) void ln_shift_kernel(const float* __restrict__ x,
                                                       const float* __restrict__ g,
                                                       const float* __restrict__ b,
                                                       u16* __restrict__ out) {
  int row  = blockIdx.x * 4 + (threadIdx.x >> 6);
  int lane = threadIdx.x & 63;
  u16* op = out + (size_t)row * CDIM + lane*4;
  int l  = row & (LSEQ-1);
  int ls = l + NSH;
  if (ls >= LSEQ) { *(ushort4*)op = make_ushort4(0,0,0,0); return; }
  const float4 v = *(const float4*)(x + ((size_t)(row - l) + ls) * CDIM + lane*4);
  float s  = v.x+v.y+v.z+v.w;
  float s2 = v.x*v.x + v.y*v.y + v.z*v.z + v.w*v.w;
#pragma unroll
  for (int m = 1; m < 64; m <<= 1) { s += __shfl_xor(s, m); s2 += __shfl_xor(s2, m); }
  float mean = s * (1.f/CDIM);
  float rs = rsqrtf(s2*(1.f/CDIM) - mean*mean + 1e-5f);
  const float4 gv = *(const float4*)(g + lane*4);
  const float4 bv = *(const float4*)(b + lane*4);
  ushort4 o;
  o.x = f2bf((v.x-mean)*rs*gv.x + bv.x);
  o.y = f2bf((v.y-mean)*rs*gv.y + bv.y);
  o.z = f2bf((v.z-mean)*rs*gv.z + bv.z);
  o.w = f2bf((v.w-mean)*rs*gv.w + bv.w);
  *(ushort4*)op = o;
}

// ---------------- LN2: fix rows l<32 of x1 (=x), LN -> bf16 ----------------
__global__ __launch_bounds__(256) void ln2_kernel(const float* __restrict__ x,
                                                  float* __restrict__ x1,
                                                  const float* __restrict__ g,
                                                  const float* __restrict__ b,
                                                  u16* __restrict__ out) {
  int row  = blockIdx.x * 4 + (threadIdx.x >> 6);
  int lane = threadIdx.x & 63;
  int l = row & (LSEQ-1);
  float* dp = x1 + (size_t)row * CDIM + lane*4;
  float4 v;
  if (l < NSH) { v = *(const float4*)(x + (size_t)row * CDIM + lane*4); *(float4*)dp = v; }
  else         { v = *(const float4*)dp; }
  float s  = v.x+v.y+v.z+v.w;
  float s2 = v.x*v.x + v.y*v.y + v.z*v.z + v.w*v.w;
#pragma unroll
  for (int m = 1; m < 64; m <<= 1) { s += __shfl_xor(s, m); s2 += __shfl_xor(s2, m); }
  float mean = s * (1.f/CDIM);
  float rs = rsqrtf(s2*(1.f/CDIM) - mean*mean + 1e-5f);
  const float4 gv = *(const float4*)(g + lane*4);
  const float4 bv = *(const float4*)(b + lane*4);
  ushort4 o;
  o.x = f2bf((v.x-mean)*rs*gv.x + bv.x);
  o.y = f2bf((v.y-mean)*rs*gv.y + bv.y);
  o.z = f2bf((v.z-mean)*rs*gv.z + bv.z);
  o.w = f2bf((v.w-mean)*rs*gv.w + bv.w);
  *(ushort4*)(out + (size_t)row * CDIM + lane*4) = o;
}

// ---------------- GEMM: C[M,N] = A[M,K] * BT[N,K]^T, 128x128x64 tiles ----------------
// 1D grid with supertile remap (G=32 tm-tiles per chunk, tn innermost).
// MFMA operands SWAPPED (mfma(bf,af)) so acc[m][n][j] = C[row0+m*16+c0][col0+n*16+g*4+j]:
// each thread owns 4 contiguous output columns -> vectorized epilogue.
// EPI: 0=bf16 +bias (qkv), 1=proj(+bias, unshift, +x residual -> fp32),
//      2=fc1(+bias, gelu -> bf16), 3=fc2(+bias, +res -> fp32)
template<int KDIM, int NDIM, int EPI>
__global__ __launch_bounds__(256) void gemm_kernel(const u16* __restrict__ A,
                                                   const u16* __restrict__ BT,
                                                   const float* __restrict__ bias,
                                                   void* __restrict__ Cout,
                                                   const float* __restrict__ res) {
  __shared__ __align__(16) u16 As[128*64];
  __shared__ __align__(16) u16 Bs[128*64];
  const int t = threadIdx.x, wave = t >> 6, lane = t & 63;
  constexpr int NT_N = NDIM / 128;
  constexpr int G = 32;
  const int bid = blockIdx.x;
  const int chunk = bid / (G * NT_N);
  const int rem = bid - chunk * (G * NT_N);
  const int tn = rem / G;
  const int tm = chunk * G + (rem - tn * G);
  f32x4 acc[4][4];
#pragma unroll
  for (int m = 0; m < 4; ++m)
#pragma unroll
    for (int n = 0; n < 4; ++n) acc[m][n] = (f32x4){0.f,0.f,0.f,0.f};

  const size_t Aoff = (size_t)tm * 128 * KDIM;
  const size_t Boff = (size_t)tn * 128 * KDIM;
  int rowS[4], kblkS[4];
#pragma unroll
  for (int p = 0; p < 4; ++p) {
    int i = p*256 + t; rowS[p] = i >> 3;
    kblkS[p] = ((i & 7) ^ (rowS[p] & 7)) * 8;   // inverse-swizzled global k-block
  }
  const int wr = (wave >> 1) * 64, wc = (wave & 1) * 64;

  for (int kt = 0; kt < KDIM/64; ++kt) {
    const int k0 = kt * 64;
#pragma unroll
    for (int p = 0; p < 4; ++p) {
      __builtin_amdgcn_global_load_lds(
        (const __attribute__((address_space(1))) void*)(A + Aoff + (size_t)rowS[p]*KDIM + k0 + kblkS[p]),
        (__attribute__((address_space(3))) void*)(As + (p*256 + wave*64)*8), 16, 0, 0);
      __builtin_amdgcn_global_load_lds(
        (const __attribute__((address_space(1))) void*)(BT + Boff + (size_t)rowS[p]*KDIM + k0 + kblkS[p]),
        (__attribute__((address_space(3))) void*)(Bs + (p*256 + wave*64)*8), 16, 0, 0);
    }
    asm volatile("s_waitcnt vmcnt(0)" ::: "memory");
    __syncthreads();
#pragma unroll
    for (int kk = 0; kk < 2; ++kk) {
      s16x8 af[4], bf[4];
#pragma unroll
      for (int m = 0; m < 4; ++m) {
        int r = wr + m*16 + (lane & 15);
        int slot = (kk*4 + (lane >> 4)) ^ (r & 7);
        af[m] = *(const s16x8*)&As[r*64 + slot*8];
      }
#pragma unroll
      for (int n = 0; n < 4; ++n) {
        int r = wc + n*16 + (lane & 15);
        int slot = (kk*4 + (lane >> 4)) ^ (r & 7);
        bf[n] = *(const s16x8*)&Bs[r*64 + slot*8];
      }
#pragma unroll
      for (int m = 0; m < 4; ++m)
#pragma unroll
        for (int n = 0; n < 4; ++n)
          acc[m][n] = __builtin_amdgcn_mfma_f32_16x16x32_bf16(bf[n], af[m], acc[m][n], 0, 0, 0);
    }
    __syncthreads();
  }

  const int g = lane >> 4, c0 = lane & 15;
  const size_t row0 = (size_t)tm*128 + wr;
  const int col0 = tn*128 + wc;
  float4 bvv[4];
#pragma unroll
  for (int n = 0; n < 4; ++n) bvv[n] = *(const float4*)(bias + col0 + n*16 + g*4);

  if constexpr (EPI == 0) {
    u16* out = (u16*)Cout;
#pragma unroll
    for (int m = 0; m < 4; ++m) {
      size_t R = row0 + m*16 + c0;
      u16* orow = out + R * NDIM + col0 + g*4;
#pragma unroll
      for (int n = 0; n < 4; ++n) {
        ushort4 o;
        o.x = f2bf(acc[m][n][0] + bvv[n].x);
        o.y = f2bf(acc[m][n][1] + bvv[n].y);
        o.z = f2bf(acc[m][n][2] + bvv[n].z);
        o.w = f2bf(acc[m][n][3] + bvv[n].w);
        *(ushort4*)(orow + n*16) = o;
      }
    }
  } else if constexpr (EPI == 1) {
    float* out = (float*)Cout;
#pragma unroll
    for (int m = 0; m < 4; ++m) {
      size_t R = row0 + m*16 + c0;
      int l = (int)(R & (LSEQ-1));
      if (l < LSEQ - NSH) {
        size_t base = (R + NSH) * CDIM + col0 + g*4;
#pragma unroll
        for (int n = 0; n < 4; ++n) {
          float4 rv = *(const float4*)(res + base + n*16);
          float4 o;
          o.x = rv.x + acc[m][n][0] + bvv[n].x;
          o.y = rv.y + acc[m][n][1] + bvv[n].y;
          o.z = rv.z + acc[m][n][2] + bvv[n].z;
          o.w = rv.w + acc[m][n][3] + bvv[n].w;
          *(float4*)(out + base + n*16) = o;
        }
      }
    }
  } else if constexpr (EPI == 2) {
    u16* out = (u16*)Cout;
#pragma unroll
    for (int m = 0; m < 4; ++m) {
      size_t R = row0 + m*16 + c0;
      u16* orow = out + R * NDIM + col0 + g*4;
#pragma unroll
      for (int n = 0; n < 4; ++n) {
        ushort4 o;
        o.x = f2bf(gelu_fast(acc[m][n][0] + bvv[n].x));
        o.y = f2bf(gelu_fast(acc[m][n][1] + bvv[n].y));
        o.z = f2bf(gelu_fast(acc[m][n][2] + bvv[n].z));
        o.w = f2bf(gelu_fast(acc[m][n][3] + bvv[n].w));
        *(ushort4*)(orow + n*16) = o;
      }
    }
  } else {
    float* out = (float*)Cout;
#pragma unroll
    for (int m = 0; m < 4; ++m) {
      size_t R = row0 + m*16 + c0;
      size_t base = R * NDIM + col0 + g*4;
#pragma unroll
      for (int n = 0; n < 4; ++n) {
        float4 rv = *(const float4*)(res + base + n*16);
        float4 o;
        o.x = rv.x + acc[m][n][0] + bvv[n].x;
        o.y = rv.y + acc[m][n][1] + bvv[n].y;
        o.z = rv.z + acc[m][n][2] + bvv[n].z;
        o.w = rv.w + acc[m][n][3] + bvv[n].w;
        *(float4*)(out + base + n*16) = o;
      }
    }
  }
}

// ---------------- windowed attention ----------------
__global__ __launch_bounds__(256) void attn_kernel(const u16* __restrict__ qkv,
                                                   const float* __restrict__ rpb,
                                                   u16* __restrict__ out) {
  __shared__ __align__(16) u16 VT[NHEADS*HDIM*NWIN]; // [h][d][c], xor-swizzled, 32KB
  __shared__ __align__(16) u16 Pl[4*NWIN*NWIN];      // per-wave P, swizzled, 32KB
  __shared__ float biasl[NHEADS][128];
  const int t = threadIdx.x, wave = t >> 6, lane = t & 63;
  const int g = lane >> 4, c0 = lane & 15;
  const size_t rowbase = (size_t)blockIdx.x * NWIN;

  for (int e = t; e < NHEADS*128; e += 256) {
    int h = e >> 7, i = e & 127;
    biasl[h][i] = (i < 2*NWIN-1) ? rpb[i*NHEADS + h] : 0.f;
  }
  { // V transpose staging: VT[h][d][c] = v[c][d]
    int cA = t >> 5;
    int inner = t & 31;
    int hh = inner >> 2, d0 = (inner & 3) * 8;
#pragma unroll
    for (int p = 0; p < 8; ++p) {
      int c = p*8 + cA;
      s16x8 v = *(const s16x8*)&qkv[(rowbase + c)*768 + 512 + hh*32 + d0];
#pragma unroll
      for (int j = 0; j < 8; ++j) {
        int d = d0 + j;
        int slot = (c >> 3) ^ (d & 7) ^ hh;
        *(u16*)((char*)VT + hh*4096 + d*128 + slot*16 + (c & 7)*2) = (u16)v[j];
      }
    }
  }
  __syncthreads();

  const float scale = 0.17677669529663687f; // 32^-0.5
#pragma unroll 1
  for (int rep = 0; rep < 2; ++rep) {
    const int h = wave*2 + rep;
    s16x8 qf[4], kf[4];
#pragma unroll
    for (int m = 0; m < 4; ++m)
      qf[m] = *(const s16x8*)&qkv[(rowbase + m*16 + c0)*768 + h*32 + g*8];
#pragma unroll
    for (int n = 0; n < 4; ++n)
      kf[n] = *(const s16x8*)&qkv[(rowbase + n*16 + c0)*768 + 256 + h*32 + g*8];
    f32x4 sa[4][4];
#pragma unroll
    for (int m = 0; m < 4; ++m)
#pragma unroll
      for (int n = 0; n < 4; ++n) sa[m][n] = (f32x4){0.f,0.f,0.f,0.f};
#pragma unroll
    for (int m = 0; m < 4; ++m)
#pragma unroll
      for (int n = 0; n < 4; ++n)
        sa[m][n] = __builtin_amdgcn_mfma_f32_16x16x32_bf16(qf[m], kf[n], sa[m][n], 0, 0, 0);
    // scale + relative position bias
#pragma unroll
    for (int m = 0; m < 4; ++m)
#pragma unroll
      for (int n = 0; n < 4; ++n) {
        int idx0 = (m-n)*16 + 4*g - c0 + 63;
#pragma unroll
        for (int j = 0; j < 4; ++j)
          sa[m][n][j] = sa[m][n][j]*scale + biasl[h][idx0 + j];
      }
    // softmax (rows spread over 16 lanes of same g-group x 4 n-regs)
    float rm[4][4], rsum[4][4];
#pragma unroll
    for (int m = 0; m < 4; ++m)
#pragma unroll
      for (int j = 0; j < 4; ++j) {
        float mx = fmaxf(fmaxf(sa[m][0][j], sa[m][1][j]), fmaxf(sa[m][2][j], sa[m][3][j]));
        mx = fmaxf(mx, __shfl_xor(mx, 1));
        mx = fmaxf(mx, __shfl_xor(mx, 2));
        mx = fmaxf(mx, __shfl_xor(mx, 4));
        mx = fmaxf(mx, __shfl_xor(mx, 8));
        rm[m][j] = mx;
      }
#pragma unroll
    for (int m = 0; m < 4; ++m)
#pragma unroll
      for (int n = 0; n < 4; ++n)
#pragma unroll
        for (int j = 0; j < 4; ++j)
          sa[m][n][j] = __expf(sa[m][n][j] - rm[m][j]);
#pragma unroll
    for (int m = 0; m < 4; ++m)
#pragma unroll
      for (int j = 0; j < 4; ++j) {
        float s = sa[m][0][j] + sa[m][1][j] + sa[m][2][j] + sa[m][3][j];
        s += __shfl_xor(s, 1);
        s += __shfl_xor(s, 2);
        s += __shfl_xor(s, 4);
        s += __shfl_xor(s, 8);
        rsum[m][j] = 1.f / s;
      }
    // write P (bf16, swizzled)
    asm volatile("s_waitcnt lgkmcnt(0)" ::: "memory");
#pragma unroll
    for (int m = 0; m < 4; ++m)
#pragma unroll
      for (int n = 0; n < 4; ++n)
#pragma unroll
        for (int j = 0; j < 4; ++j) {
          int r = m*16 + 4*g + j, c = n*16 + c0;
          *(u16*)((char*)Pl + wave*8192 + r*128 + (((c>>3)^(r&7))*16) + (c&7)*2)
            = f2bf(sa[m][n][j] * rsum[m][j]);
        }
    asm volatile("s_waitcnt lgkmcnt(0)" ::: "memory");
    __builtin_amdgcn_sched_barrier(0);
    // PV (operands swapped: oa[m][n][j] = O[row m*16+c0][d n*16+g*4+j])
    f32x4 oa[4][2];
#pragma unroll
    for (int m = 0; m < 4; ++m) { oa[m][0] = (f32x4){0.f,0.f,0.f,0.f}; oa[m][1] = (f32x4){0.f,0.f,0.f,0.f}; }
#pragma unroll
    for (int kk = 0; kk < 2; ++kk) {
      s16x8 pa[4], vb[2];
#pragma unroll
      for (int m = 0; m < 4; ++m) {
        int r = m*16 + c0;
        int slot = (kk*4 + g) ^ (r & 7);
        pa[m] = *(const s16x8*)((const char*)Pl + wave*8192 + r*128 + slot*16);
      }
#pragma unroll
      for (int n = 0; n < 2; ++n) {
        int d = n*16 + c0;
        int slot = (kk*4 + g) ^ (d & 7) ^ h;
        vb[n] = *(const s16x8*)((const char*)VT + h*4096 + d*128 + slot*16);
      }
#pragma unroll
      for (int m = 0; m < 4; ++m)
#pragma unroll
        for (int n = 0; n < 2; ++n)
          oa[m][n] = __builtin_amdgcn_mfma_f32_16x16x32_bf16(vb[n], pa[m], oa[m][n], 0, 0, 0);
    }
#pragma unroll
    for (int m = 0; m < 4; ++m) {
      u16* op = out + (rowbase + m*16 + c0)*CDIM + h*32 + g*4;
#pragma unroll
      for (int n = 0; n < 2; ++n) {
        ushort4 o;
        o.x = f2bf(oa[m][n][0]); o.y = f2bf(oa[m][n][1]);
        o.z = f2bf(oa[m][n][2]); o.w = f2bf(oa[m][n][3]);
        *(ushort4*)(op + n*16) = o;
      }
    }
  }
}

extern "C" void kernel_launch(void* const* d_in, const int* in_sizes, int n_in,
                              void* d_out, int out_size, void* d_ws, size_t ws_size,
                              hipStream_t stream) {
  const float* x      = (const float*)d_in[0];
  const float* g1     = (const float*)d_in[1];
  const float* b1     = (const float*)d_in[2];
  const float* qkv_w  = (const float*)d_in[3];
  const float* qkv_b  = (const float*)d_in[4];
  const float* rpb    = (const float*)d_in[5];
  const float* proj_w = (const float*)d_in[6];
  const float* proj_b = (const float*)d_in[7];
  const float* g2     = (const float*)d_in[8];
  const float* b2     = (const float*)d_in[9];
  const float* fc1_w  = (const float*)d_in[10];
  const float* fc1_b  = (const float*)d_in[11];
  const float* fc2_w  = (const float*)d_in[12];
  const float* fc2_b  = (const float*)d_in[13];
  float* out = (float*)d_out;

  u16* R0     = (u16*)d_ws;
  u16* R1     = R0 + (size_t)MROWS*768;
  u16* qkvwT  = R1 + (size_t)MROWS*1024;
  u16* projwT = qkvwT + 768*256;
  u16* fc1wT  = projwT + 256*256;
  u16* fc2wT  = fc1wT + 1024*256;

  wtrans_kernel<<<dim3(4, 12), 256, 0, stream>>>(qkv_w, qkvwT, 256, 768);
  wtrans_kernel<<<dim3(4, 4),  256, 0, stream>>>(proj_w, projwT, 256, 256);
  wtrans_kernel<<<dim3(4, 16), 256, 0, stream>>>(fc1_w, fc1wT, 256, 1024);
  wtrans_kernel<<<dim3(16, 4), 256, 0, stream>>>(fc2_w, fc2wT, 1024, 256);

  constexpr int NT_M = MROWS/128;
  ln_shift_kernel<<<MROWS/4, 256, 0, stream>>>(x, g1, b1, R1);
  gemm_kernel<256, 768, 0><<<NT_M*6, 256, 0, stream>>>(R1, qkvwT, qkv_b, R0, nullptr);
  attn_kernel<<<MROWS/NWIN, 256, 0, stream>>>(R0, rpb, R1);
  gemm_kernel<256, 256, 1><<<NT_M*2, 256, 0, stream>>>(R1, projwT, proj_b, out, x);
  ln2_kernel<<<MROWS/4, 256, 0, stream>>>(x, out, g2, b2, R0);
  gemm_kernel<256, 1024, 2><<<NT_M*8, 256, 0, stream>>>(R0, fc1wT, fc1_b, R1, nullptr);
  gemm_kernel<1024, 256, 3><<<NT_M*2, 256, 0, stream>>>(R1, fc2wT, fc2_b, out, out);
}